// Round 1
// baseline (348.204 us; speedup 1.0000x reference)
//
#include <hip/hip_runtime.h>
#include <math.h>

#define BATCHN 65536
#define INPUTN 128
#define HIDDENN 512

// ---------------------------------------------------------------------------
// Kernel 0: build the fixed 16x16 unitary U_g for each gate g (batch-independent
// part of the circuit: 2 layers of [CNOT ring; RX,RY,RZ per qubit]).
// Thread t = (g<<4)|col simulates basis state |col> through the fixed circuit.
// U[(g*16+m)*16+col] = amplitude m of U_g |col>.
// ---------------------------------------------------------------------------
__global__ void k_build_u(const float* __restrict__ qwF, const float* __restrict__ qwI,
                          const float* __restrict__ qwO, const float* __restrict__ qwC,
                          float2* __restrict__ U) {
  int t = threadIdx.x;
  if (t >= 64) return;
  int g = t >> 4, col = t & 15;
  const float* qw = (g == 0) ? qwF : (g == 1) ? qwI : (g == 2) ? qwO : qwC;

  float sr[16], si[16];
#pragma unroll
  for (int i = 0; i < 16; i++) { sr[i] = (i == col) ? 1.f : 0.f; si[i] = 0.f; }

#pragma unroll
  for (int l = 0; l < 2; l++) {
    // CNOT ring: control j, target (j+1)%4.  new[i] = old[ i has control bit ? i^targetbit : i ]
#pragma unroll
    for (int j = 0; j < 4; j++) {
      const int bc = 8 >> j;
      const int bt = 8 >> ((j + 1) & 3);
      float tr[16], ti[16];
#pragma unroll
      for (int i = 0; i < 16; i++) {
        int src = (i & bc) ? (i ^ bt) : i;
        tr[i] = sr[src]; ti[i] = si[src];
      }
#pragma unroll
      for (int i = 0; i < 16; i++) { sr[i] = tr[i]; si[i] = ti[i]; }
    }
    // rotations per qubit
#pragma unroll
    for (int j = 0; j < 4; j++) {
      const int bit = 8 >> j;
      const float thx = qw[(l * 4 + j) * 3 + 0] * 0.5f;
      const float thy = qw[(l * 4 + j) * 3 + 1] * 0.5f;
      const float thz = qw[(l * 4 + j) * 3 + 2] * 0.5f;
      float c, s;
      // RX: [[c, -i s], [-i s, c]]
      c = cosf(thx); s = sinf(thx);
#pragma unroll
      for (int i = 0; i < 16; i++) if (!(i & bit)) {
        const int k2 = i | bit;
        const float ar = sr[i], ai = si[i], br = sr[k2], bi = si[k2];
        sr[i]  = c * ar + s * bi;  si[i]  = c * ai - s * br;
        sr[k2] = c * br + s * ai;  si[k2] = c * bi - s * ar;
      }
      // RY: [[c, -s], [s, c]] (real)
      c = cosf(thy); s = sinf(thy);
#pragma unroll
      for (int i = 0; i < 16; i++) if (!(i & bit)) {
        const int k2 = i | bit;
        const float ar = sr[i], ai = si[i], br = sr[k2], bi = si[k2];
        sr[i]  = c * ar - s * br;  si[i]  = c * ai - s * bi;
        sr[k2] = s * ar + c * br;  si[k2] = s * ai + c * bi;
      }
      // RZ: diag(e^{-i th}, e^{+i th}), th = thz
      c = cosf(thz); s = sinf(thz);
#pragma unroll
      for (int i = 0; i < 16; i++) if (!(i & bit)) {
        const int k2 = i | bit;
        const float ar = sr[i], ai = si[i], br = sr[k2], bi = si[k2];
        sr[i]  = c * ar + s * ai;  si[i]  = c * ai - s * ar;
        sr[k2] = c * br - s * bi;  si[k2] = c * bi + s * br;
      }
    }
  }
#pragma unroll
  for (int m = 0; m < 16; m++)
    U[(g * 16 + m) * 16 + col] = make_float2(sr[m], si[m]);
}

// ---------------------------------------------------------------------------
// Kernel 1: per (row, gate-pair): angles = row . PW^T + pb  (8 dots of len 640),
// then quantum sim in registers -> q[b][gate*4+j].
// blockIdx parity selects gate pair so all W accesses are wave-uniform (s_load).
// Adjacent blocks (same rows, different pair) co-scheduled -> L2 reuse of x/h.
// ---------------------------------------------------------------------------
__global__ __launch_bounds__(256) void k_proj_q(
    const float* __restrict__ x, const float* __restrict__ hprev,
    const float* __restrict__ pwF, const float* __restrict__ pbF,
    const float* __restrict__ pwI, const float* __restrict__ pbI,
    const float* __restrict__ pwO, const float* __restrict__ pbO,
    const float* __restrict__ pwC, const float* __restrict__ pbC,
    const float2* __restrict__ U, float* __restrict__ qv) {
  const int bid = blockIdx.x;
  const int hp = bid & 1;                     // 0: gates {forget,input}; 1: {output,cell}
  const int b = (bid >> 1) * 256 + threadIdx.x;

  const float* pw0 = hp ? pwO : pwF;
  const float* pb0 = hp ? pbO : pbF;
  const float* pw1 = hp ? pwC : pwI;
  const float* pb1 = hp ? pbC : pbI;

  float acc[8];
#pragma unroll
  for (int j = 0; j < 4; j++) { acc[j] = pb0[j]; acc[4 + j] = pb1[j]; }

  const float* xr = x + (size_t)b * INPUTN;
  const float* hr = hprev + (size_t)b * HIDDENN;

#pragma unroll 4
  for (int k = 0; k < INPUTN; k += 4) {
    const float4 a = *(const float4*)(xr + k);
#pragma unroll
    for (int j = 0; j < 4; j++) {
      const float4 w0 = *(const float4*)(pw0 + j * 640 + k);
      const float4 w1 = *(const float4*)(pw1 + j * 640 + k);
      acc[j]     += a.x * w0.x + a.y * w0.y + a.z * w0.z + a.w * w0.w;
      acc[4 + j] += a.x * w1.x + a.y * w1.y + a.z * w1.z + a.w * w1.w;
    }
  }
#pragma unroll 4
  for (int k = 0; k < HIDDENN; k += 4) {
    const float4 a = *(const float4*)(hr + k);
#pragma unroll
    for (int j = 0; j < 4; j++) {
      const float4 w0 = *(const float4*)(pw0 + INPUTN + j * 640 + k);
      const float4 w1 = *(const float4*)(pw1 + INPUTN + j * 640 + k);
      acc[j]     += a.x * w0.x + a.y * w0.y + a.z * w0.z + a.w * w0.w;
      acc[4 + j] += a.x * w1.x + a.y * w1.y + a.z * w1.z + a.w * w1.w;
    }
  }

  // quantum part for the two gates of this pair
#pragma unroll
  for (int gl = 0; gl < 2; gl++) {
    float cs[4], sn[4];
#pragma unroll
    for (int j = 0; j < 4; j++) __sincosf(acc[gl * 4 + j] * 0.5f, &sn[j], &cs[j]);
    // product state after the data-encoding RY layer (all real, psi0[c] = prod cos/sin)
    float psi[16];
#pragma unroll
    for (int c16 = 0; c16 < 16; c16++) {
      float p = ((c16 & 8) ? sn[0] : cs[0]);
      p *= ((c16 & 4) ? sn[1] : cs[1]);
      p *= ((c16 & 2) ? sn[2] : cs[2]);
      p *= ((c16 & 1) ? sn[3] : cs[3]);
      psi[c16] = p;
    }
    const int gg = hp * 2 + gl;
    const float2* Ug = U + gg * 256;
    float q0 = 0.f, q1 = 0.f, q2 = 0.f, q3 = 0.f;
#pragma unroll
    for (int m = 0; m < 16; m++) {
      float ssr = 0.f, ssi = 0.f;
#pragma unroll
      for (int c16 = 0; c16 < 16; c16++) {
        const float2 u = Ug[m * 16 + c16];
        ssr += u.x * psi[c16];
        ssi += u.y * psi[c16];
      }
      const float p = ssr * ssr + ssi * ssi;
      q0 = (m & 8) ? q0 - p : q0 + p;
      q1 = (m & 4) ? q1 - p : q1 + p;
      q2 = (m & 2) ? q2 - p : q2 + p;
      q3 = (m & 1) ? q3 - p : q3 + p;
    }
    *(float4*)(qv + (size_t)b * 16 + gg * 4) = make_float4(q0, q1, q2, q3);
  }
}

// ---------------------------------------------------------------------------
// Kernel 2: expansion 4 -> 512 per gate + LSTM elementwise. Block per row,
// thread handles 4 h's (float4). q is wave-uniform; lw/lb L2-resident.
// ---------------------------------------------------------------------------
__device__ __forceinline__ float sigmf(float v) { return 1.f / (1.f + __expf(-v)); }
__device__ __forceinline__ float tanhfast(float v) { return 1.f - 2.f / (__expf(2.f * v) + 1.f); }

__global__ __launch_bounds__(128) void k_lstm(
    const float* __restrict__ qv, const float* __restrict__ cprev,
    const float* __restrict__ lwF, const float* __restrict__ lbF,
    const float* __restrict__ lwI, const float* __restrict__ lbI,
    const float* __restrict__ lwO, const float* __restrict__ lbO,
    const float* __restrict__ lwC, const float* __restrict__ lbC,
    float* __restrict__ out) {
  const int b = blockIdx.x;
  const int h0 = threadIdx.x * 4;
  const float* q = qv + (size_t)b * 16;
  float qF[4], qI[4], qO[4], qC[4];
#pragma unroll
  for (int j = 0; j < 4; j++) { qF[j] = q[j]; qI[j] = q[4 + j]; qO[j] = q[8 + j]; qC[j] = q[12 + j]; }

  const float4 cp = *(const float4*)(cprev + (size_t)b * HIDDENN + h0);
  const float4 bF = *(const float4*)(lbF + h0);
  const float4 bI = *(const float4*)(lbI + h0);
  const float4 bO = *(const float4*)(lbO + h0);
  const float4 bC = *(const float4*)(lbC + h0);

  float hn[4], cn[4];
#pragma unroll
  for (int hh = 0; hh < 4; hh++) {
    const float4 wF = *(const float4*)(lwF + (size_t)(h0 + hh) * 4);
    const float4 wI = *(const float4*)(lwI + (size_t)(h0 + hh) * 4);
    const float4 wO = *(const float4*)(lwO + (size_t)(h0 + hh) * 4);
    const float4 wC = *(const float4*)(lwC + (size_t)(h0 + hh) * 4);
    const float pf = ((const float*)&bF)[hh] + wF.x * qF[0] + wF.y * qF[1] + wF.z * qF[2] + wF.w * qF[3];
    const float pi = ((const float*)&bI)[hh] + wI.x * qI[0] + wI.y * qI[1] + wI.z * qI[2] + wI.w * qI[3];
    const float po = ((const float*)&bO)[hh] + wO.x * qO[0] + wO.y * qO[1] + wO.z * qO[2] + wO.w * qO[3];
    const float pg = ((const float*)&bC)[hh] + wC.x * qC[0] + wC.y * qC[1] + wC.z * qC[2] + wC.w * qC[3];
    const float f  = sigmf(pf);
    const float ii = sigmf(pi);
    const float oo = sigmf(po);
    const float gg = tanhfast(pg);
    const float cc = f * ((const float*)&cp)[hh] + ii * gg;
    cn[hh] = cc;
    hn[hh] = oo * tanhfast(cc);
  }
  *(float4*)(out + (size_t)b * HIDDENN + h0) = make_float4(hn[0], hn[1], hn[2], hn[3]);
  *(float4*)(out + (size_t)BATCHN * HIDDENN + (size_t)b * HIDDENN + h0) = make_float4(cn[0], cn[1], cn[2], cn[3]);
}

// ---------------------------------------------------------------------------
extern "C" void kernel_launch(void* const* d_in, const int* in_sizes, int n_in,
                              void* d_out, int out_size, void* d_ws, size_t ws_size,
                              hipStream_t stream) {
  const float* x  = (const float*)d_in[0];
  const float* h  = (const float*)d_in[1];
  const float* c  = (const float*)d_in[2];
  const float* pwF = (const float*)d_in[3];
  const float* pbF = (const float*)d_in[4];
  const float* qwF = (const float*)d_in[5];
  const float* lwF = (const float*)d_in[6];
  const float* lbF = (const float*)d_in[7];
  const float* pwI = (const float*)d_in[8];
  const float* pbI = (const float*)d_in[9];
  const float* qwI = (const float*)d_in[10];
  const float* lwI = (const float*)d_in[11];
  const float* lbI = (const float*)d_in[12];
  const float* pwO = (const float*)d_in[13];
  const float* pbO = (const float*)d_in[14];
  const float* qwO = (const float*)d_in[15];
  const float* lwO = (const float*)d_in[16];
  const float* lbO = (const float*)d_in[17];
  const float* pwC = (const float*)d_in[18];
  const float* pbC = (const float*)d_in[19];
  const float* qwC = (const float*)d_in[20];
  const float* lwC = (const float*)d_in[21];
  const float* lbC = (const float*)d_in[22];

  float* ws = (float*)d_ws;
  float* qv = ws;                                  // BATCHN*16 floats (4 MB)
  float2* U = (float2*)(ws + (size_t)BATCHN * 16); // 4*16*16 float2 (8 KB)

  k_build_u<<<dim3(1), dim3(64), 0, stream>>>(qwF, qwI, qwO, qwC, U);
  k_proj_q<<<dim3(512), dim3(256), 0, stream>>>(x, h, pwF, pbF, pwI, pbI, pwO, pbO,
                                                pwC, pbC, U, qv);
  k_lstm<<<dim3(BATCHN), dim3(128), 0, stream>>>(qv, c, lwF, lbF, lwI, lbI, lwO, lbO,
                                                 lwC, lbC, (float*)d_out);
}

// Round 2
// 262.706 us; speedup vs baseline: 1.3254x; 1.3254x over previous
//
#include <hip/hip_runtime.h>
#include <math.h>

#define BATCHN 65536
#define INPUTN 128
#define HIDDENN 512

// ---------------------------------------------------------------------------
// Kernel 0: build the fixed 16x16 unitary U_g for each gate g (batch-independent
// part of the circuit: 2 layers of [CNOT ring; RX,RY,RZ per qubit]).
// Thread t = (g<<4)|col simulates basis state |col>.
// ---------------------------------------------------------------------------
__global__ void k_build_u(const float* __restrict__ qwF, const float* __restrict__ qwI,
                          const float* __restrict__ qwO, const float* __restrict__ qwC,
                          float2* __restrict__ U) {
  int t = threadIdx.x;
  if (t >= 64) return;
  int g = t >> 4, col = t & 15;
  const float* qw = (g == 0) ? qwF : (g == 1) ? qwI : (g == 2) ? qwO : qwC;

  float sr[16], si[16];
#pragma unroll
  for (int i = 0; i < 16; i++) { sr[i] = (i == col) ? 1.f : 0.f; si[i] = 0.f; }

#pragma unroll
  for (int l = 0; l < 2; l++) {
#pragma unroll
    for (int j = 0; j < 4; j++) {
      const int bc = 8 >> j;
      const int bt = 8 >> ((j + 1) & 3);
      float tr[16], ti[16];
#pragma unroll
      for (int i = 0; i < 16; i++) {
        int src = (i & bc) ? (i ^ bt) : i;
        tr[i] = sr[src]; ti[i] = si[src];
      }
#pragma unroll
      for (int i = 0; i < 16; i++) { sr[i] = tr[i]; si[i] = ti[i]; }
    }
#pragma unroll
    for (int j = 0; j < 4; j++) {
      const int bit = 8 >> j;
      const float thx = qw[(l * 4 + j) * 3 + 0] * 0.5f;
      const float thy = qw[(l * 4 + j) * 3 + 1] * 0.5f;
      const float thz = qw[(l * 4 + j) * 3 + 2] * 0.5f;
      float c, s;
      c = cosf(thx); s = sinf(thx);           // RX
#pragma unroll
      for (int i = 0; i < 16; i++) if (!(i & bit)) {
        const int k2 = i | bit;
        const float ar = sr[i], ai = si[i], br = sr[k2], bi = si[k2];
        sr[i]  = c * ar + s * bi;  si[i]  = c * ai - s * br;
        sr[k2] = c * br + s * ai;  si[k2] = c * bi - s * ar;
      }
      c = cosf(thy); s = sinf(thy);           // RY
#pragma unroll
      for (int i = 0; i < 16; i++) if (!(i & bit)) {
        const int k2 = i | bit;
        const float ar = sr[i], ai = si[i], br = sr[k2], bi = si[k2];
        sr[i]  = c * ar - s * br;  si[i]  = c * ai - s * bi;
        sr[k2] = s * ar + c * br;  si[k2] = s * ai + c * bi;
      }
      c = cosf(thz); s = sinf(thz);           // RZ
#pragma unroll
      for (int i = 0; i < 16; i++) if (!(i & bit)) {
        const int k2 = i | bit;
        const float ar = sr[i], ai = si[i], br = sr[k2], bi = si[k2];
        sr[i]  = c * ar + s * ai;  si[i]  = c * ai - s * ar;
        sr[k2] = c * br - s * bi;  si[k2] = c * bi + s * br;
      }
    }
  }
#pragma unroll
  for (int m = 0; m < 16; m++)
    U[(g * 16 + m) * 16 + col] = make_float2(sr[m], si[m]);
}

// ---------------------------------------------------------------------------
// Kernel 1: one GATE per block (bid&3), 256 rows per block -> 4 accumulators,
// 4096 waves total (4/SIMD) for latency hiding. x/h re-reads across the 4
// gate-blocks of a row-set are served by L2/L3 (x+h = 160 MB < 256 MB L3).
// ---------------------------------------------------------------------------
__global__ __launch_bounds__(256) void k_proj_q(
    const float* __restrict__ x, const float* __restrict__ hprev,
    const float* __restrict__ pwF, const float* __restrict__ pbF,
    const float* __restrict__ pwI, const float* __restrict__ pbI,
    const float* __restrict__ pwO, const float* __restrict__ pbO,
    const float* __restrict__ pwC, const float* __restrict__ pbC,
    const float2* __restrict__ U, float* __restrict__ qv) {
  const int bid = blockIdx.x;
  const int g = bid & 3;
  const int b = (bid >> 2) * 256 + threadIdx.x;

  const float* pw = (g == 0) ? pwF : (g == 1) ? pwI : (g == 2) ? pwO : pwC;
  const float* pb = (g == 0) ? pbF : (g == 1) ? pbI : (g == 2) ? pbO : pbC;

  float acc[4];
#pragma unroll
  for (int j = 0; j < 4; j++) acc[j] = pb[j];

  const float* xr = x + (size_t)b * INPUTN;
  const float* hr = hprev + (size_t)b * HIDDENN;

#pragma unroll 4
  for (int k = 0; k < INPUTN; k += 4) {
    const float4 a = *(const float4*)(xr + k);
#pragma unroll
    for (int j = 0; j < 4; j++) {
      const float4 w = *(const float4*)(pw + j * 640 + k);
      acc[j] += a.x * w.x + a.y * w.y + a.z * w.z + a.w * w.w;
    }
  }
#pragma unroll 4
  for (int k = 0; k < HIDDENN; k += 4) {
    const float4 a = *(const float4*)(hr + k);
#pragma unroll
    for (int j = 0; j < 4; j++) {
      const float4 w = *(const float4*)(pw + INPUTN + j * 640 + k);
      acc[j] += a.x * w.x + a.y * w.y + a.z * w.z + a.w * w.w;
    }
  }

  // quantum part for this gate
  float cs[4], sn[4];
#pragma unroll
  for (int j = 0; j < 4; j++) __sincosf(acc[j] * 0.5f, &sn[j], &cs[j]);
  float psi[16];
#pragma unroll
  for (int c16 = 0; c16 < 16; c16++) {
    float p = ((c16 & 8) ? sn[0] : cs[0]);
    p *= ((c16 & 4) ? sn[1] : cs[1]);
    p *= ((c16 & 2) ? sn[2] : cs[2]);
    p *= ((c16 & 1) ? sn[3] : cs[3]);
    psi[c16] = p;
  }
  const float2* Ug = U + g * 256;
  float q0 = 0.f, q1 = 0.f, q2 = 0.f, q3 = 0.f;
#pragma unroll
  for (int m = 0; m < 16; m++) {
    float ssr = 0.f, ssi = 0.f;
#pragma unroll
    for (int c16 = 0; c16 < 16; c16++) {
      const float2 u = Ug[m * 16 + c16];
      ssr += u.x * psi[c16];
      ssi += u.y * psi[c16];
    }
    const float p = ssr * ssr + ssi * ssi;
    q0 = (m & 8) ? q0 - p : q0 + p;
    q1 = (m & 4) ? q1 - p : q1 + p;
    q2 = (m & 2) ? q2 - p : q2 + p;
    q3 = (m & 1) ? q3 - p : q3 + p;
  }
  *(float4*)(qv + (size_t)b * 16 + g * 4) = make_float4(q0, q1, q2, q3);
}

// ---------------------------------------------------------------------------
// Kernel 2: LSTM expansion. Each thread OWNS 4 h-positions: weights (16 float4)
// and biases live in registers, loaded once; the thread then loops over 8 rows
// (2 rows in flight per iteration via the tid>>7 half-split). Weight L1 traffic
// drops 8x vs round-1. Divisions replaced by v_rcp_f32.
// ---------------------------------------------------------------------------
__device__ __forceinline__ float sigmf(float v) {
  return __builtin_amdgcn_rcpf(1.f + __expf(-v));
}
__device__ __forceinline__ float tanhfast(float v) {
  return 1.f - 2.f * __builtin_amdgcn_rcpf(__expf(2.f * v) + 1.f);
}

__global__ __launch_bounds__(256) void k_lstm(
    const float* __restrict__ qv, const float* __restrict__ cprev,
    const float* __restrict__ lwF, const float* __restrict__ lbF,
    const float* __restrict__ lwI, const float* __restrict__ lbI,
    const float* __restrict__ lwO, const float* __restrict__ lbO,
    const float* __restrict__ lwC, const float* __restrict__ lbC,
    float* __restrict__ out) {
  const int tid = threadIdx.x;
  const int half = tid >> 7;            // which row of the in-flight pair
  const int h0 = (tid & 127) * 4;       // 4 h-positions owned by this thread
  const int rb = blockIdx.x * 8;        // 8 rows per block

  // weights/biases in registers, loaded once (L1-resident across blocks)
  float4 wF[4], wI[4], wO[4], wC[4];
#pragma unroll
  for (int hh = 0; hh < 4; hh++) {
    wF[hh] = *(const float4*)(lwF + (size_t)(h0 + hh) * 4);
    wI[hh] = *(const float4*)(lwI + (size_t)(h0 + hh) * 4);
    wO[hh] = *(const float4*)(lwO + (size_t)(h0 + hh) * 4);
    wC[hh] = *(const float4*)(lwC + (size_t)(h0 + hh) * 4);
  }
  const float4 bF = *(const float4*)(lbF + h0);
  const float4 bI = *(const float4*)(lbI + h0);
  const float4 bO = *(const float4*)(lbO + h0);
  const float4 bC = *(const float4*)(lbC + h0);

#pragma unroll
  for (int it = 0; it < 4; it++) {
    const int r = rb + it * 2 + half;
    const float* q = qv + (size_t)r * 16;
    const float4 qF = *(const float4*)(q);      // wave-uniform addresses
    const float4 qI = *(const float4*)(q + 4);
    const float4 qO = *(const float4*)(q + 8);
    const float4 qC = *(const float4*)(q + 12);
    const float4 cp = *(const float4*)(cprev + (size_t)r * HIDDENN + h0);

    float hn[4], cn[4];
#pragma unroll
    for (int hh = 0; hh < 4; hh++) {
      const float pf = ((const float*)&bF)[hh] + wF[hh].x * qF.x + wF[hh].y * qF.y + wF[hh].z * qF.z + wF[hh].w * qF.w;
      const float pi = ((const float*)&bI)[hh] + wI[hh].x * qI.x + wI[hh].y * qI.y + wI[hh].z * qI.z + wI[hh].w * qI.w;
      const float po = ((const float*)&bO)[hh] + wO[hh].x * qO.x + wO[hh].y * qO.y + wO[hh].z * qO.z + wO[hh].w * qO.w;
      const float pg = ((const float*)&bC)[hh] + wC[hh].x * qC.x + wC[hh].y * qC.y + wC[hh].z * qC.z + wC[hh].w * qC.w;
      const float f  = sigmf(pf);
      const float ii = sigmf(pi);
      const float oo = sigmf(po);
      const float gg = tanhfast(pg);
      const float cc = f * ((const float*)&cp)[hh] + ii * gg;
      cn[hh] = cc;
      hn[hh] = oo * tanhfast(cc);
    }
    *(float4*)(out + (size_t)r * HIDDENN + h0) = make_float4(hn[0], hn[1], hn[2], hn[3]);
    *(float4*)(out + (size_t)BATCHN * HIDDENN + (size_t)r * HIDDENN + h0) = make_float4(cn[0], cn[1], cn[2], cn[3]);
  }
}

// ---------------------------------------------------------------------------
extern "C" void kernel_launch(void* const* d_in, const int* in_sizes, int n_in,
                              void* d_out, int out_size, void* d_ws, size_t ws_size,
                              hipStream_t stream) {
  const float* x  = (const float*)d_in[0];
  const float* h  = (const float*)d_in[1];
  const float* c  = (const float*)d_in[2];
  const float* pwF = (const float*)d_in[3];
  const float* pbF = (const float*)d_in[4];
  const float* qwF = (const float*)d_in[5];
  const float* lwF = (const float*)d_in[6];
  const float* lbF = (const float*)d_in[7];
  const float* pwI = (const float*)d_in[8];
  const float* pbI = (const float*)d_in[9];
  const float* qwI = (const float*)d_in[10];
  const float* lwI = (const float*)d_in[11];
  const float* lbI = (const float*)d_in[12];
  const float* pwO = (const float*)d_in[13];
  const float* pbO = (const float*)d_in[14];
  const float* qwO = (const float*)d_in[15];
  const float* lwO = (const float*)d_in[16];
  const float* lbO = (const float*)d_in[17];
  const float* pwC = (const float*)d_in[18];
  const float* pbC = (const float*)d_in[19];
  const float* qwC = (const float*)d_in[20];
  const float* lwC = (const float*)d_in[21];
  const float* lbC = (const float*)d_in[22];

  float* ws = (float*)d_ws;
  float* qv = ws;                                  // BATCHN*16 floats (4 MB)
  float2* U = (float2*)(ws + (size_t)BATCHN * 16); // 4*16*16 float2 (8 KB)

  k_build_u<<<dim3(1), dim3(64), 0, stream>>>(qwF, qwI, qwO, qwC, U);
  k_proj_q<<<dim3(1024), dim3(256), 0, stream>>>(x, h, pwF, pbF, pwI, pbI, pwO, pbO,
                                                 pwC, pbC, U, qv);
  k_lstm<<<dim3(BATCHN / 8), dim3(256), 0, stream>>>(qv, c, lwF, lbF, lwI, lbI, lwO, lbO,
                                                     lwC, lbC, (float*)d_out);
}